// Round 6
// baseline (264.901 us; speedup 1.0000x reference)
//
#include <hip/hip_runtime.h>
#include <hip/hip_bf16.h>
#include <math.h>

// Problem constants (from reference): B=4, S=2048, n_head=32, h_dim=128
// Dtype map (established rounds 0-3): ALL inputs fp32, output fp32.
// (Harness compares in bf16 domain, but buffers are fp32.)
#define SEQ_LEN 2048
#define NROWS (4 * 2048 * 32)      // 262144 head-rows of 128
#define NSTRIPS (NROWS / 16)       // 16384 strips of 16 rows

typedef short bf16x8 __attribute__((ext_vector_type(8)));  // 8 bf16 = 4 VGPR (MFMA A/B frag)
typedef float f32x4 __attribute__((ext_vector_type(4)));   // MFMA C/D frag

__device__ __forceinline__ unsigned short f2bf(float f) {
    union { float f; unsigned int i; } v; v.f = f;
    unsigned int r = v.i + 0x7FFFu + ((v.i >> 16) & 1u);  // round-to-nearest-even
    return (unsigned short)(r >> 16);
}

// ---------------------------------------------------------------------------
// prep: M = A_0 * ... * A_63 * R  (y = x @ M), built in fp32 LDS, rounded to
// bf16, stored pre-swizzled in 16x16x32 B-fragment order with a column
// permutation chosen so the MAIN kernel's C-layout is STORE-CONTIGUOUS and
// RoPE pairs are lane-local:
//   B-slot n = 16*nt + m  <-  y-column src(n) = (nt<4) ? 8m+2*nt
//                                             : 8m+2*(nt-4)+1
// Main kernel then has, at lane (q,m):  acc[nt] = y[2c], acc[nt+4] = y[2c+1]
// with c = 4m+nt — out cols 4m..4m+3 (and 64+...) are lane-local consecutive
// floats -> f32x4 stores, each 128B line written whole by one instruction.
// ---------------------------------------------------------------------------
__global__ void prep_kernel(const float* __restrict__ thetas,
                            const float* __restrict__ pairs,
                            const float* __restrict__ tscale,
                            const float* __restrict__ rotmat,
                            unsigned short* __restrict__ Bsw) {
    __shared__ float M[128][128];   // 64 KB
    __shared__ float Cv[64], Sv[64];
    __shared__ int   Iv[64], Jv[64];
    const int t = threadIdx.x;      // 256 threads
    if (t < 64) {                   // parallel trig + index precompute
        const float th = thetas[t] * tscale[0];
        Cv[t] = cosf(th);
        Sv[t] = sinf(th);
        int i = (int)pairs[2 * t];
        int j = (int)pairs[2 * t + 1];
        Iv[t] = min(max(i, 0), 127);
        Jv[t] = min(max(j, 0), 127);
    }
    // coalesced load: M[d][c] = rotmat[d*128+c], linear over 16384 floats
    float* Mf = &M[0][0];
#pragma unroll 8
    for (int idx = t; idx < 128 * 128; idx += 256) Mf[idx] = rotmat[idx];
    __syncthreads();
    // Left-mult by A_r for r = 63 down to 0. Givens left-mult touches only
    // rows i,j of M -> column-private per thread (threads 0..127), no syncs.
    if (t < 128) {
        for (int r = 63; r >= 0; --r) {
            const int i = Iv[r], j = Jv[r];
            const float c = Cv[r], s = Sv[r];
            if (i == j) {
                M[i][t] *= c;
            } else {
                const float a = M[i][t], b = M[j][t];
                M[i][t] = c * a - s * b;   // (A M)[i,:] = c*M[i,:] - s*M[j,:]
                M[j][t] = s * a + c * b;   // (A M)[j,:] = s*M[i,:] + c*M[j,:]
            }
        }
    }
    __syncthreads();
    for (int idx = t; idx < 32 * 64; idx += 256) {
        const int f = idx >> 6, lane = idx & 63;
        const int kk = f >> 3, nt = f & 7;
        const int krow = kk * 32 + (lane >> 4) * 8;
        const int m = lane & 15;
        // store-contiguous + lane-local RoPE-pair permutation
        const int col = (nt < 4) ? (8 * m + 2 * nt) : (8 * m + 2 * (nt - 4) + 1);
        unsigned short* dst = Bsw + (size_t)idx * 8;
#pragma unroll
        for (int j2 = 0; j2 < 8; ++j2) dst[j2] = f2bf(M[krow + j2][col]);
    }
}

// ---------------------------------------------------------------------------
// main (round 6): MAX-TLP structure. Round-5 post-mortem: per-wave prefetch
// is repeatedly defeated by the compiler at the 64-VGPR budget, and pipe-work
// accounting (~22us of total pipe busy vs 81us wall, all util counters <7%)
// shows the kernel is stall-bound: waves have loads in flight only ~5% of
// their lifetime, and at 10-16 waves/CU that leaves ~2-4 KB/CU in flight vs
// the ~9 KB Little's-law requirement for full HBM rate.
// Fix: share ONE 32 KB B-copy among 16 waves -> 1024-thread blocks, grid=512
// = exactly 2 resident blocks/CU -> 32 waves/CU (hardware max), 64 KB LDS/CU.
// __launch_bounds__(1024,8) pins VGPR<=64 (R4 compiled this compute at 48).
// Each wave: 2 strips, simple R4-style load->compute (no manual prefetch --
// TLP, not ILP, supplies the memory-level parallelism).
// Traffic must stay at R4's clean level: FETCH ~66 MB, WRITE ~131 MB.
// ---------------------------------------------------------------------------
__global__ __launch_bounds__(1024, 8) void rope_kernel(
        const float* __restrict__ x,
        const unsigned short* __restrict__ Bsw,
        const float* __restrict__ invfreq,
        float* __restrict__ out) {
    __shared__ f32x4 Blds[2048];           // 32 KB: B fragments, frag-order
    const int tid = threadIdx.x;           // 0..1023
    const int lane = tid & 63;
    const int w = tid >> 6;                // wave 0..15 in block
    {   // direct global->LDS staging: wave w covers f32x4 slots
        // [i*1024 + w*64, +64): lds dest = uniform base + lane*16 (linear ok)
        const char* gbase = (const char*)Bsw;
#pragma unroll
        for (int i = 0; i < 2; ++i) {
            const int fi = i * 1024 + w * 64;
            __builtin_amdgcn_global_load_lds(
                (const __attribute__((address_space(1))) unsigned int*)
                    (gbase + (size_t)(fi + lane) * 16),
                (__attribute__((address_space(3))) unsigned int*)&Blds[fi],
                16, 0, 0);
        }
    }

    const int wave = (int)(blockIdx.x * 16 + w);   // 0..8191
    const int m = lane & 15;
    const int quad = lane >> 4;
    const bf16x8* Bf = (const bf16x8*)Blds;
    const float invf = invfreq[lane];  // lane k <-> frequency k (64 freqs)

    __syncthreads();   // B staged (drains global_load_lds), LDS ready

#pragma unroll
    for (int half = 0; half < 2; ++half) {
        const int s = wave + half * 8192;          // strip id, 0..16383
        const int r0 = s * 16;
        const float* xrow = x + (size_t)(r0 + m) * 128 + quad * 8;
        f32x4 lo[4], hi[4];
#pragma unroll
        for (int kk = 0; kk < 4; ++kk) {
            lo[kk] = *(const f32x4*)(xrow + kk * 32);
            hi[kk] = *(const f32x4*)(xrow + kk * 32 + 4);
        }

        // all 16 rows of the strip share one sequence position
        const int s_pos = (s >> 1) & (SEQ_LEN - 1);
        float sn_l, cs_l;
        sincosf((float)s_pos * invf, &sn_l, &cs_l);  // lane k: sin/cos freq k

        bf16x8 A[4];
#pragma unroll
        for (int kk = 0; kk < 4; ++kk) {
            union { __hip_bfloat162 h; unsigned int u; } c0, c1, c2, c3;
            c0.h = __float22bfloat162_rn(make_float2(lo[kk][0], lo[kk][1]));
            c1.h = __float22bfloat162_rn(make_float2(lo[kk][2], lo[kk][3]));
            c2.h = __float22bfloat162_rn(make_float2(hi[kk][0], hi[kk][1]));
            c3.h = __float22bfloat162_rn(make_float2(hi[kk][2], hi[kk][3]));
            union { unsigned int u[4]; bf16x8 v; } a;
            a.u[0] = c0.u; a.u[1] = c1.u; a.u[2] = c2.u; a.u[3] = c3.u;
            A[kk] = a.v;
        }

        f32x4 acc[8];
#pragma unroll
        for (int nt = 0; nt < 8; ++nt) acc[nt] = (f32x4){0.f, 0.f, 0.f, 0.f};

#pragma unroll
        for (int kk = 0; kk < 4; ++kk)
#pragma unroll
            for (int nt = 0; nt < 8; ++nt)
                acc[nt] = __builtin_amdgcn_mfma_f32_16x16x32_bf16(
                    A[kk], Bf[(kk * 8 + nt) * 64 + lane], acc[nt], 0, 0, 0);

        // epilogue: lane (q,m): acc[nt] = y[2c], acc[nt+4] = y[2c+1], c=4m+nt
        float cs[4], sn[4];
#pragma unroll
        for (int nt = 0; nt < 4; ++nt) {
            cs[nt] = __shfl(cs_l, 4 * m + nt, 64);
            sn[nt] = __shfl(sn_l, 4 * m + nt, 64);
        }
        float* orow = out + (size_t)(r0 + quad * 4) * 128;
#pragma unroll
        for (int rr = 0; rr < 4; ++rr) {
            f32x4 ve, vo;
#pragma unroll
            for (int nt = 0; nt < 4; ++nt) {
                const float ye = acc[nt][rr];       // y[2c]
                const float yo = acc[nt + 4][rr];   // y[2c+1]
                ve[nt] = ye * cs[nt] - yo * sn[nt];
                vo[nt] = ye * sn[nt] + yo * cs[nt];
            }
            *(f32x4*)(orow + (size_t)rr * 128 + 4 * m)      = ve;
            *(f32x4*)(orow + (size_t)rr * 128 + 64 + 4 * m) = vo;
        }
    }
}

extern "C" void kernel_launch(void* const* d_in, const int* in_sizes, int n_in,
                              void* d_out, int out_size, void* d_ws, size_t ws_size,
                              hipStream_t stream) {
    const float* x      = (const float*)d_in[0];   // fp32
    const float* thetas = (const float*)d_in[1];   // fp32
    const float* pairs  = (const float*)d_in[2];   // fp32
    const float* tscale = (const float*)d_in[3];   // fp32
    const float* rotmat = (const float*)d_in[4];   // fp32
    const float* invfr  = (const float*)d_in[5];   // fp32
    // d_in[6] = n_head (int, ==32) — baked into constants
    float* out = (float*)d_out;                    // fp32
    unsigned short* Bsw = (unsigned short*)d_ws;   // 32 KB used

    prep_kernel<<<1, 256, 0, stream>>>(thetas, pairs, tscale, rotmat, Bsw);
    rope_kernel<<<512, 1024, 0, stream>>>(x, Bsw, invfr, out);
}